// Round 6
// baseline (190.530 us; speedup 1.0000x reference)
//
#include <hip/hip_runtime.h>

// GraphSAGE mean-aggregate + linear (no bias): out = segment_mean(x[src] by dst) @ W^T
// x: [50000, 64] f32, edge_index: [2, 800000] int32, W: [128, 64] f32,
// out: [50000, 128] f32.
//
// Pipeline (3 dispatches):
//   memset(cursor) -> bin (bucket sort by dst/196, LDS-staged, coalesced)
//   -> fused (per 49-node slice: LDS-local CSR build + register gather +
//      mean + W^T epilogue, W staged once per block, out written directly).

constexpr int N_NODES = 50000;
constexpr int N_EDGES = 800000;
constexpr int IN_CH   = 64;
constexpr int HID_CH  = 128;

constexpr int NBKT          = 256;
constexpr int NODES_PER_BKT = 196;   // 256*196 = 50176 >= 50000; bucket = dst/196
constexpr int BKT_CAP       = 4096;  // mean 3125, +17 sigma -> safe
constexpr int CHUNK         = 4096;  // edges per binning block
constexpr int NBIN_BLOCKS   = (N_EDGES + CHUNK - 1) / CHUNK;  // 196

constexpr int SUB  = 4;              // fused blocks per bucket
constexpr int NPS  = NODES_PER_BKT / SUB;  // 49 nodes per fused block
constexpr int SCAP = 1024;           // per-slice edge cap: mean 781, +8.7 sigma

// ---- pass 1: bucket-bin edges. LDS histogram + local sort, coalesced out ----
__global__ __launch_bounds__(256) void bin_kernel(
    const int* __restrict__ ei,
    int* __restrict__ cursor,                       // [NBKT], zeroed
    unsigned long long* __restrict__ binned)        // [NBKT][BKT_CAP] (dst<<32)|src
{
    __shared__ int hist[NBKT];
    __shared__ int scan[NBKT];
    __shared__ int lexcl[NBKT];
    __shared__ int lcur[NBKT];
    __shared__ int res[NBKT];
    __shared__ unsigned long long stage[CHUNK];

    const int t  = threadIdx.x;
    const int e0 = blockIdx.x * CHUNK;
    const int nE = min(N_EDGES - e0, CHUNK);

    hist[t] = 0;
    __syncthreads();

    int srcs[16], dsts[16];
    #pragma unroll
    for (int q = 0; q < 4; ++q) {
        const int idx = t * 16 + q * 4;
        if (idx < nE) {  // nE % 4 == 0 always
            const int4 s4 = *reinterpret_cast<const int4*>(ei + e0 + idx);
            const int4 d4 = *reinterpret_cast<const int4*>(ei + N_EDGES + e0 + idx);
            srcs[q * 4 + 0] = s4.x; srcs[q * 4 + 1] = s4.y;
            srcs[q * 4 + 2] = s4.z; srcs[q * 4 + 3] = s4.w;
            dsts[q * 4 + 0] = d4.x; dsts[q * 4 + 1] = d4.y;
            dsts[q * 4 + 2] = d4.z; dsts[q * 4 + 3] = d4.w;
            atomicAdd(&hist[d4.x / NODES_PER_BKT], 1);
            atomicAdd(&hist[d4.y / NODES_PER_BKT], 1);
            atomicAdd(&hist[d4.z / NODES_PER_BKT], 1);
            atomicAdd(&hist[d4.w / NODES_PER_BKT], 1);
        } else {
            srcs[q*4+0]=srcs[q*4+1]=srcs[q*4+2]=srcs[q*4+3]=0;
            dsts[q*4+0]=dsts[q*4+1]=dsts[q*4+2]=dsts[q*4+3]=0;
        }
    }
    __syncthreads();

    const int hv = hist[t];
    scan[t] = hv;
    __syncthreads();
    for (int off = 1; off < NBKT; off <<= 1) {
        const int u = (t >= off) ? scan[t - off] : 0;
        __syncthreads();
        scan[t] += u;
        __syncthreads();
    }
    const int myExcl = scan[t] - hv;
    lexcl[t] = myExcl;
    lcur[t]  = myExcl;
    res[t]   = (hv > 0) ? atomicAdd(&cursor[t], hv) : 0;
    __syncthreads();

    #pragma unroll
    for (int q = 0; q < 16; ++q) {
        const int idx = t * 16 + q;
        if (idx < nE) {
            const int bkt = dsts[q] / NODES_PER_BKT;
            const int p = atomicAdd(&lcur[bkt], 1);
            stage[p] = ((unsigned long long)(unsigned)dsts[q] << 32) | (unsigned)srcs[q];
        }
    }
    __syncthreads();

    for (int i = t; i < nE; i += 256) {
        const unsigned long long v = stage[i];
        const int bkt = (int)(v >> 32) / NODES_PER_BKT;
        const int p = res[bkt] + (i - lexcl[bkt]);
        if (p < BKT_CAP) binned[(size_t)bkt * BKT_CAP + p] = v;
    }
}

// ---- pass 2 (fused): one block per 49-node slice of a bucket.
//      LDS-local CSR build -> register gather -> mean + W^T -> out. ----
__global__ __launch_bounds__(256) void fused_kernel(
    const unsigned long long* __restrict__ binned,
    const int* __restrict__ cursor,
    const float* __restrict__ x,
    const float* __restrict__ W,
    float* __restrict__ out)
{
    __shared__ float4 sW4[16][HID_CH + 1];   // [k4][o] = W[o][4k4..+3]
    __shared__ int   ldeg[64];
    __shared__ int   loffs[64];
    __shared__ int   lcur[64];
    __shared__ int   stage_src[SCAP];
    __shared__ float4 sA4[4][4][16];          // [wave][j][k4] scaled means

    const int bb  = blockIdx.x;
    const int b   = bb >> 2;           // bucket
    const int sub = bb & 3;            // slice within bucket
    const int lo  = b * NODES_PER_BKT + sub * NPS;  // nodes [lo, lo+NPS)
    const int t   = threadIdx.x;

    // Stage W (long-latency loads issued first).
    #pragma unroll
    for (int r = 0; r < 8; ++r) {
        const int i = t + r * 256;
        const int o = i >> 4, k4 = i & 15;
        sW4[k4][o] = *reinterpret_cast<const float4*>(W + (size_t)o * IN_CH + k4 * 4);
    }
    if (t < 64) ldeg[t] = 0;
    __syncthreads();

    const int cnt = min(cursor[b], BKT_CAP);

    // Load bucket edges to registers; histogram our slice.
    unsigned long long ev[16];
    #pragma unroll
    for (int q = 0; q < 16; ++q) {
        const int i = t + q * 256;
        ev[q] = 0xffffffff00000000ull;  // out-of-range sentinel
        if (i < cnt) ev[q] = binned[(size_t)b * BKT_CAP + i];
    }
    #pragma unroll
    for (int q = 0; q < 16; ++q) {
        const int loc = (int)(ev[q] >> 32) - lo;
        if ((unsigned)loc < (unsigned)NPS) atomicAdd(&ldeg[loc], 1);
    }
    __syncthreads();

    // Wave 0: 64-wide shfl_up exclusive scan of ldeg.
    if (t < 64) {
        const int v = ldeg[t];
        int incl = v;
        #pragma unroll
        for (int off = 1; off < 64; off <<= 1) {
            const int u = __shfl_up(incl, off, 64);
            incl += (t >= off) ? u : 0;
        }
        loffs[t] = incl - v;
        lcur[t]  = incl - v;
    }
    __syncthreads();

    // Scatter srcs into local CSR order.
    #pragma unroll
    for (int q = 0; q < 16; ++q) {
        const int loc = (int)(ev[q] >> 32) - lo;
        if ((unsigned)loc < (unsigned)NPS) {
            const int p = atomicAdd(&lcur[loc], 1);
            if (p < SCAP) stage_src[p] = (int)(ev[q] & 0xffffffffu);
        }
    }
    __syncthreads();

    // Gather + mean + linear. 4 waves; wave w owns nodes {nb + j*4 + w}.
    const int wave = t >> 6;
    const int lane = t & 63;
    const int grp  = lane >> 4;   // edge slot within a 4-edge group
    const int ch4  = lane & 15;   // float4 channel slot

    for (int nb = 0; nb < 64; nb += 16) {   // 4 uniform batches
        #pragma unroll
        for (int j = 0; j < 4; ++j) {
            const int loc = nb + j * 4 + wave;
            float a0 = 0.f, a1 = 0.f, a2 = 0.f, a3 = 0.f;
            int d = 0;
            if (loc < NPS) d = ldeg[loc];
            const int beg = (loc < NPS) ? loffs[loc] : 0;
            for (int i = 0; i < d; i += 8) {   // 8 edges per iter (2 rows/lane in flight)
                const int eA = i + grp;
                const int eB = i + 4 + grp;
                const int sA = stage_src[beg + min(eA, d - 1)];
                const int sB = stage_src[beg + min(eB, d - 1)];
                const float fA = (eA < d) ? 1.f : 0.f;
                const float fB = (eB < d) ? 1.f : 0.f;
                const float4 vA = *reinterpret_cast<const float4*>(x + (size_t)sA * IN_CH + ch4 * 4);
                const float4 vB = *reinterpret_cast<const float4*>(x + (size_t)sB * IN_CH + ch4 * 4);
                a0 = fmaf(fA, vA.x, a0); a1 = fmaf(fA, vA.y, a1);
                a2 = fmaf(fA, vA.z, a2); a3 = fmaf(fA, vA.w, a3);
                a0 = fmaf(fB, vB.x, a0); a1 = fmaf(fB, vB.y, a1);
                a2 = fmaf(fB, vB.z, a2); a3 = fmaf(fB, vB.w, a3);
            }
            // Merge the 4 edge groups.
            #pragma unroll
            for (int m = 16; m <= 32; m <<= 1) {
                a0 += __shfl_xor(a0, m, 64);
                a1 += __shfl_xor(a1, m, 64);
                a2 += __shfl_xor(a2, m, 64);
                a3 += __shfl_xor(a3, m, 64);
            }
            if (lane < 16) {
                const float inv = 1.0f / fmaxf((float)d, 1.0f);
                float4 r{a0 * inv, a1 * inv, a2 * inv, a3 * inv};
                sA4[wave][j][ch4] = r;
            }
        }
        // Same-wave LDS write -> read: drain DS queue; memory clobber orders
        // the following ds_reads; sched_barrier pins codegen (rule #18).
        __asm__ volatile("s_waitcnt lgkmcnt(0)" ::: "memory");
        __builtin_amdgcn_sched_barrier(0);

        float acc[4][2] = {{0.f,0.f},{0.f,0.f},{0.f,0.f},{0.f,0.f}};
        #pragma unroll
        for (int k4 = 0; k4 < 16; ++k4) {
            const float4 w0 = sW4[k4][lane];
            const float4 w1 = sW4[k4][lane + 64];
            #pragma unroll
            for (int j = 0; j < 4; ++j) {
                const float4 a = sA4[wave][j][k4];  // broadcast read
                acc[j][0] += a.x * w0.x + a.y * w0.y + a.z * w0.z + a.w * w0.w;
                acc[j][1] += a.x * w1.x + a.y * w1.y + a.z * w1.z + a.w * w1.w;
            }
        }
        #pragma unroll
        for (int j = 0; j < 4; ++j) {
            const int loc = nb + j * 4 + wave;
            const int n = lo + loc;
            if (loc < NPS && n < N_NODES) {
                const size_t row = (size_t)n * HID_CH;
                out[row + lane]      = acc[j][0];
                out[row + 64 + lane] = acc[j][1];
            }
        }
    }
}

extern "C" void kernel_launch(void* const* d_in, const int* in_sizes, int n_in,
                              void* d_out, int out_size, void* d_ws, size_t ws_size,
                              hipStream_t stream) {
    const float* x   = (const float*)d_in[0];
    const int*   ei  = (const int*)  d_in[1];
    const float* W   = (const float*)d_in[2];
    float*       out = (float*)d_out;

    unsigned long long* binned = (unsigned long long*)d_ws;      // NBKT*BKT_CAP (8 MB)
    int* cursor = (int*)(binned + (size_t)NBKT * BKT_CAP);       // [NBKT]

    hipMemsetAsync(cursor, 0, NBKT * sizeof(int), stream);
    bin_kernel<<<NBIN_BLOCKS, 256, 0, stream>>>(ei, cursor, binned);
    fused_kernel<<<NBKT * SUB, 256, 0, stream>>>(binned, cursor, x, W, out);
}